// Round 4
// baseline (209.152 us; speedup 1.0000x reference)
//
#include <hip/hip_runtime.h>
#include <hip/hip_fp16.h>

// Panorama: warp frame (4,1080,1920) via homography onto canvas (4,2048,3072),
// alpha-over composite. float32 in/out.
//
// R4: frame packed to interleaved fp16 RGBA (8 B/px) in d_ws. Each bilinear
// row-tap-pair (x0, x0+1) is ONE 16 B gather. 2 px/thread in x so canvas/out
// use float2. VMEM instrs: 6/px (was 12/px in R3). fp16 adds <=5e-4 abs error
// (threshold 2e-2); alpha==1.0 is exact in fp16.

#define FH 1080
#define FW 1920
#define CHh 2048
#define CWw 3072
#define FHW (FH * FW)
#define CHW (CHh * CWw)

__device__ __forceinline__ unsigned pack2(float a, float b) {
    union { __half2 h; unsigned u; } c;
    c.h = __floats2half2_rn(a, b);
    return c.u;
}
__device__ __forceinline__ float2 unpack2(unsigned u) {
    union { unsigned u; __half2 h; } c;
    c.u = u;
    return __half22float2(c.h);
}

// prepass: planar float RGBA -> interleaved fp16 RGBA (8 B/px)
__global__ __launch_bounds__(256) void pack_kernel(
    const float* __restrict__ frame, uint2* __restrict__ fi)
{
    const int idx = blockIdx.x * 256 + threadIdx.x;   // FHW == 8100*256
    uint2 u;
    u.x = pack2(frame[idx],           frame[FHW + idx]);      // r,g
    u.y = pack2(frame[2 * FHW + idx], frame[3 * FHW + idx]);  // b,a
    fi[idx] = u;
}

__global__ __launch_bounds__(256) void pano2_kernel(
    const uint2* __restrict__ fi,
    const float* __restrict__ Hm,
    const float* __restrict__ canvas,
    float* __restrict__ out)
{
    const int xp = blockIdx.x * 256 + threadIdx.x;   // pixel-pair index, CWw/2 per row
    const int y  = blockIdx.y;
    const int q  = y * (CWw / 2) + xp;               // float2 index within a plane

    // canvas loads first — independent of the gather chain
    const float2* cv = (const float2*)canvas;
    const float2 cr = cv[0 * (CHW / 2) + q];
    const float2 cg = cv[1 * (CHW / 2) + q];
    const float2 cb = cv[2 * (CHW / 2) + q];
    const float2 ca = cv[3 * (CHW / 2) + q];

    const float a  = Hm[0], b  = Hm[1], c  = Hm[2];
    const float d  = Hm[3], e  = Hm[4], f  = Hm[5];
    const float g  = Hm[6], hh = Hm[7], i9 = Hm[8];
    // adjugate (1/det cancels in perspective divide)
    const float A0 = e * i9 - f * hh, A1 = c * hh - b * i9, A2 = b * f - c * e;
    const float B0 = f * g  - d * i9, B1 = a * i9 - c * g,  B2 = c * d - a * f;
    const float C0 = d * hh - e * g,  C1 = b * g  - a * hh, C2 = a * e - b * d;

    float wr[2], wg[2], wb[2], wa[2];
    const float yf = (float)y;

    #pragma unroll
    for (int p = 0; p < 2; ++p) {
        wr[p] = wg[p] = wb[p] = wa[p] = 0.f;
        const float xf = (float)(2 * xp + p);
        const float u = fmaf(A0, xf, fmaf(A1, yf, A2));
        const float v = fmaf(B0, xf, fmaf(B1, yf, B2));
        const float w = fmaf(C0, xf, fmaf(C1, yf, C2));
        const float invw = __builtin_amdgcn_rcpf(w);
        const float sx = u * invw;
        const float sy = v * invw;

        const float x0f = floorf(sx);
        const float y0f = floorf(sy);
        const float wx = sx - x0f;
        const float wy = sy - y0f;
        const int x0 = (int)x0f;
        const int y0 = (int)y0f;

        if (x0 >= -1 && x0 <= FW - 1 && y0 >= -1 && y0 <= FH - 1) {
            const int y1 = y0 + 1;
            const float mx0 = (x0 >= 0) ? 1.f : 0.f;          // x0 <= FW-1 given
            const float mx1 = (x0 + 1 <= FW - 1) ? 1.f : 0.f; // x1 >= 0  given
            const float my0 = (y0 >= 0) ? 1.f : 0.f;
            const float my1 = (y1 <= FH - 1) ? 1.f : 0.f;

            // pair base clamped so the 16B load covers two real pixels
            const int bse = min(max(x0, 0), FW - 2);
            const bool sel = (x0 == bse);   // lo/hi order of (v00,v01) in the pair
            const int yc0 = min(max(y0, 0), FH - 1);
            const int yc1 = min(max(y1, 0), FH - 1);

            // one 16B gather per row: pixels (bse, bse+1), 8-byte aligned
            const uint4 r0 = *(const uint4*)((const char*)fi + (size_t)(yc0 * FW + bse) * 8u);
            const uint4 r1 = *(const uint4*)((const char*)fi + (size_t)(yc1 * FW + bse) * 8u);

            // select uints, then decode (values are real frame data — no NaN)
            const unsigned u00a = sel ? r0.x : r0.z, u00b = sel ? r0.y : r0.w;
            const unsigned u01a = sel ? r0.z : r0.x, u01b = sel ? r0.w : r0.y;
            const unsigned u10a = sel ? r1.x : r1.z, u10b = sel ? r1.y : r1.w;
            const unsigned u11a = sel ? r1.z : r1.x, u11b = sel ? r1.w : r1.y;

            const float2 v00rg = unpack2(u00a), v00ba = unpack2(u00b);
            const float2 v01rg = unpack2(u01a), v01ba = unpack2(u01b);
            const float2 v10rg = unpack2(u10a), v10ba = unpack2(u10b);
            const float2 v11rg = unpack2(u11a), v11ba = unpack2(u11b);

            const float w00 = (1.f - wx) * (1.f - wy) * mx0 * my0;
            const float w01 = wx * (1.f - wy) * mx1 * my0;
            const float w10 = (1.f - wx) * wy * mx0 * my1;
            const float w11 = wx * wy * mx1 * my1;

            wr[p] = fmaf(w00, v00rg.x, fmaf(w01, v01rg.x, fmaf(w10, v10rg.x, w11 * v11rg.x)));
            wg[p] = fmaf(w00, v00rg.y, fmaf(w01, v01rg.y, fmaf(w10, v10rg.y, w11 * v11rg.y)));
            wb[p] = fmaf(w00, v00ba.x, fmaf(w01, v01ba.x, fmaf(w10, v10ba.x, w11 * v11ba.x)));
            wa[p] = fmaf(w00, v00ba.y, fmaf(w01, v01ba.y, fmaf(w10, v10ba.y, w11 * v11ba.y)));
        }
    }

    float2 o0, o1, o2, o3;
    {
        const float k0 = ca.x * (1.f - wa[0]);
        const float k1 = ca.y * (1.f - wa[1]);
        o0 = make_float2(fmaf(wr[0], wa[0], cr.x * k0), fmaf(wr[1], wa[1], cr.y * k1));
        o1 = make_float2(fmaf(wg[0], wa[0], cg.x * k0), fmaf(wg[1], wa[1], cg.y * k1));
        o2 = make_float2(fmaf(wb[0], wa[0], cb.x * k0), fmaf(wb[1], wa[1], cb.y * k1));
        o3 = make_float2(wa[0] + k0, wa[1] + k1);
    }

    float2* ov = (float2*)out;
    ov[0 * (CHW / 2) + q] = o0;
    ov[1 * (CHW / 2) + q] = o1;
    ov[2 * (CHW / 2) + q] = o2;
    ov[3 * (CHW / 2) + q] = o3;
}

// ---- fallback (planar, no ws) ----
__global__ __launch_bounds__(256) void pano_kernel(
    const float* __restrict__ frame,
    const float* __restrict__ Hm,
    const float* __restrict__ canvas,
    float* __restrict__ out)
{
    const int x = blockIdx.x * 256 + threadIdx.x;
    const int y = blockIdx.y;
    const int pix = y * CWw + x;

    const float a  = Hm[0], b  = Hm[1], c  = Hm[2];
    const float d  = Hm[3], e  = Hm[4], f  = Hm[5];
    const float g  = Hm[6], hh = Hm[7], i9 = Hm[8];
    const float A0 = e * i9 - f * hh, A1 = c * hh - b * i9, A2 = b * f - c * e;
    const float B0 = f * g  - d * i9, B1 = a * i9 - c * g,  B2 = c * d - a * f;
    const float C0 = d * hh - e * g,  C1 = b * g  - a * hh, C2 = a * e - b * d;

    const float xf = (float)x, yf = (float)y;
    const float u = A0 * xf + A1 * yf + A2;
    const float v = B0 * xf + B1 * yf + B2;
    const float w = C0 * xf + C1 * yf + C2;
    const float sx = u / w;
    const float sy = v / w;

    const float x0f = floorf(sx);
    const float y0f = floorf(sy);
    const float wx = sx - x0f;
    const float wy = sy - y0f;
    const int x0 = (int)x0f;
    const int y0 = (int)y0f;

    const float c0 = canvas[0 * CHW + pix];
    const float c1 = canvas[1 * CHW + pix];
    const float c2 = canvas[2 * CHW + pix];
    const float ac = canvas[3 * CHW + pix];

    float w0 = 0.f, w1 = 0.f, w2 = 0.f, as = 0.f;
    if (x0 >= -1 && x0 <= FW - 1 && y0 >= -1 && y0 <= FH - 1) {
        const int x1 = x0 + 1, y1 = y0 + 1;
        const float mx0 = (x0 >= 0) ? 1.f : 0.f;
        const float mx1 = (x1 <= FW - 1) ? 1.f : 0.f;
        const float my0 = (y0 >= 0) ? 1.f : 0.f;
        const float my1 = (y1 <= FH - 1) ? 1.f : 0.f;
        const int xc0 = min(max(x0, 0), FW - 1);
        const int xc1 = min(max(x1, 0), FW - 1);
        const int yc0 = min(max(y0, 0), FH - 1);
        const int yc1 = min(max(y1, 0), FH - 1);

        const float w00 = (1.f - wx) * (1.f - wy) * mx0 * my0;
        const float w01 = wx * (1.f - wy) * mx1 * my0;
        const float w10 = (1.f - wx) * wy * mx0 * my1;
        const float w11 = wx * wy * mx1 * my1;

        const int i00 = yc0 * FW + xc0;
        const int i01 = yc0 * FW + xc1;
        const int i10 = yc1 * FW + xc0;
        const int i11 = yc1 * FW + xc1;

        #pragma unroll
        for (int chn = 0; chn < 4; ++chn) {
            const float* fp = frame + chn * FHW;
            const float val = w00 * fp[i00] + w01 * fp[i01]
                            + w10 * fp[i10] + w11 * fp[i11];
            if (chn == 0) w0 = val;
            else if (chn == 1) w1 = val;
            else if (chn == 2) w2 = val;
            else as = val;
        }
    }

    const float k = ac * (1.f - as);
    out[0 * CHW + pix] = w0 * as + c0 * k;
    out[1 * CHW + pix] = w1 * as + c1 * k;
    out[2 * CHW + pix] = w2 * as + c2 * k;
    out[3 * CHW + pix] = as + k;
}

extern "C" void kernel_launch(void* const* d_in, const int* in_sizes, int n_in,
                              void* d_out, int out_size, void* d_ws, size_t ws_size,
                              hipStream_t stream) {
    const float* frame  = (const float*)d_in[0];
    const float* Hm     = (const float*)d_in[1];
    const float* canvas = (const float*)d_in[2];
    float* out = (float*)d_out;

    const size_t need = (size_t)FHW * sizeof(uint2);   // 16,588,800 B
    if (ws_size >= need) {
        uint2* fi = (uint2*)d_ws;
        pack_kernel<<<dim3(FHW / 256), dim3(256), 0, stream>>>(frame, fi);
        pano2_kernel<<<dim3(CWw / 2 / 256, CHh), dim3(256), 0, stream>>>(fi, Hm, canvas, out);
    } else {
        pano_kernel<<<dim3(CWw / 256, CHh), dim3(256), 0, stream>>>(frame, Hm, canvas, out);
    }
}